// Round 7
// baseline (1179.057 us; speedup 1.0000x reference)
//
#include <hip/hip_runtime.h>
#include <hip/hip_bf16.h>
#include <math.h>

// ---------------------------------------------------------------------------
// GCN pair scorer, split-bf16 MFMA GEMMs (3-product hi/lo ~ fp32 accuracy).
// Round 7: XCD-sliced aggregation (slice = blockIdx%8 -> per-XCD L2-resident
// 3.75MB table slice), batched weight conversion (1 launch), 3-phase scan.
// GEMM pipeline unchanged from round 6 (241us GEMM1, matched prediction).
// ---------------------------------------------------------------------------

#define NNODES 30000
#define NEDGES 480000
#define NPAIRS 4096

typedef __attribute__((ext_vector_type(8))) short short8;
typedef __attribute__((ext_vector_type(4))) float f32x4;
typedef unsigned short u16;

__device__ __forceinline__ u16 f2bf(float x) {
    union { float f; unsigned u; } v; v.f = x;
    unsigned u = v.u;
    return (u16)((u + 0x7FFFu + ((u >> 16) & 1u)) >> 16);
}
__device__ __forceinline__ float bf2f(u16 h) {
    union { float f; unsigned u; } v; v.u = ((unsigned)h) << 16;
    return v.f;
}

// async global->LDS, 16B per lane; LDS dest = wave-uniform base + lane*16
__device__ __forceinline__ void gll16(const u16* g, u16* l) {
    __builtin_amdgcn_global_load_lds(
        (const __attribute__((address_space(1))) unsigned int*)g,
        (__attribute__((address_space(3))) unsigned int*)l, 16, 0, 0);
}

// ---------------- graph prep ----------------

__global__ void k_count(const int* __restrict__ dst, unsigned* __restrict__ cnt, int E) {
    int e = blockIdx.x * blockDim.x + threadIdx.x;
    if (e < E) atomicAdd(&cnt[dst[e]], 1u);
}

__global__ void k_dinv(const unsigned* __restrict__ cnt, float* __restrict__ dinv, int N) {
    int n = blockIdx.x * blockDim.x + threadIdx.x;
    if (n < N) {
        float deg = (float)(cnt[n] + 1u);
        dinv[n] = 1.0f / sqrtf(deg);
    }
}

// 3-phase scan: per-block inclusive -> serial scan of partials -> add offsets
__global__ void k_scan1(const unsigned* __restrict__ cnt, unsigned* __restrict__ loc,
                        unsigned* __restrict__ part, int N) {
    __shared__ unsigned buf[256];
    int i = blockIdx.x * 256 + threadIdx.x;
    unsigned v = (i < N) ? cnt[i] : 0u;
    buf[threadIdx.x] = v;
    __syncthreads();
    for (int off = 1; off < 256; off <<= 1) {
        unsigned t = (threadIdx.x >= (unsigned)off) ? buf[threadIdx.x - off] : 0u;
        __syncthreads();
        buf[threadIdx.x] += t;
        __syncthreads();
    }
    if (i < N) loc[i] = buf[threadIdx.x];
    if (threadIdx.x == 255) part[blockIdx.x] = buf[255];
}

__global__ void k_scan2(unsigned* __restrict__ part, int nb) {
    if (threadIdx.x == 0 && blockIdx.x == 0) {
        unsigned s = 0;
        for (int i = 0; i < nb; ++i) { unsigned t = part[i]; part[i] = s; s += t; }
    }
}

__global__ void k_scan3(const unsigned* __restrict__ loc, const unsigned* __restrict__ part,
                        unsigned* __restrict__ rowptr, int N) {
    int i = blockIdx.x * 256 + threadIdx.x;
    if (i < N) rowptr[i + 1] = loc[i] + part[blockIdx.x];
    if (i == 0) rowptr[0] = 0;
}

__global__ void k_fill(const int* __restrict__ src, const int* __restrict__ dst,
                       const unsigned* __restrict__ rowptr, unsigned* __restrict__ cursor,
                       int* __restrict__ colsrc, int E) {
    int e = blockIdx.x * blockDim.x + threadIdx.x;
    if (e < E) {
        int d = dst[e];
        unsigned p = atomicAdd(&cursor[d], 1u);
        colsrc[rowptr[d] + p] = src[e];
    }
}

// ---------------- conversions ----------------

struct WJob { const float* W; u16* Th; u16* Tl; int K, N, Kp, Np, endBlk; };
struct WJobs { WJob j[10]; };

// one launch converts all 10 weight matrices: W[K][N] f32 -> [Np][Kp] pair
__global__ void k_wconv_all(WJobs js) {
    const int b = blockIdx.x;
    WJob jb = js.j[0];
    int blk0 = 0;
#pragma unroll
    for (int t = 1; t < 10; ++t)
        if (b >= js.j[t - 1].endBlk) { jb = js.j[t]; blk0 = js.j[t - 1].endBlk; }
    int idx = (b - blk0) * 256 + threadIdx.x;
    if (idx >= jb.Np * jb.Kp) return;
    int n = idx / jb.Kp, k = idx - n * jb.Kp;
    float v = (n < jb.N && k < jb.K) ? jb.W[(size_t)k * jb.N + n] : 0.f;
    u16 h = f2bf(v);
    jb.Th[idx] = h;
    jb.Tl[idx] = f2bf(v - bf2f(h));
}

// cid [30000][881] f32 -> [30080][896] bf16 hi/lo (pad cols zero)
__global__ void k_aconv(const float* __restrict__ A, u16* __restrict__ Hh,
                        u16* __restrict__ Hl) {
    int idx = blockIdx.x * blockDim.x + threadIdx.x;
    if (idx >= NNODES * 896) return;
    int row = idx / 896, col = idx - row * 896;
    float v = (col < 881) ? A[(size_t)row * 881 + col] : 0.f;
    u16 h = f2bf(v);
    Hh[idx] = h;
    Hl[idx] = f2bf(v - bf2f(h));
}

// ---------------- split-bf16 MFMA GEMM, m97 structure ----------------------
// ASRC: 0 = f32 A (issue-early reg loads + convert + ds_write), 1 = pair A (gll)
// EPI : 0 = none, 1 = relu(z+bias), 2 = max(z+bias-thr, 0)
// OUTM: 0 = f32 C, 1 = bf16 hi/lo pair C (cols >= Ntrue zeroed),
//       2 = f32 C scaled by rowscale[m]

template <int ASRC, int EPI, int OUTM>
__global__ __launch_bounds__(256) void k_mgemm(
    const float* __restrict__ Af, int ldAf, int Ktrue,
    const u16* __restrict__ Ahi, const u16* __restrict__ Alo, int ldA,
    const u16* __restrict__ Bhi, const u16* __restrict__ Blo, int ldB,
    const float* __restrict__ bias, const float* __restrict__ thrp,
    const float* __restrict__ rowscale,
    float* __restrict__ Cf, u16* __restrict__ Chi, u16* __restrict__ Clo,
    int ldC, int M, int Ntrue, int K, int gy) {
    __shared__ alignas(16) u16 Ah[128 * 32];
    __shared__ alignas(16) u16 Al[128 * 32];
    __shared__ alignas(16) u16 Bh[128 * 32];
    __shared__ alignas(16) u16 Bl[128 * 32];
    const int t = threadIdx.x;
    const int lane = t & 63, w = t >> 6;
    const int wr = w >> 1, wc = w & 1;
    const int r16 = lane & 15, kg = lane >> 4;
    // bijective XCD swizzle (m204); y (col-panel) fastest -> A-stripe L2-hot
    const int nwg = gridDim.x;
    const int q = nwg >> 3, r = nwg & 7;
    const int xcd = blockIdx.x & 7, pos = blockIdx.x >> 3;
    const int wg = (xcd < r ? xcd * (q + 1) : r * (q + 1) + (xcd - r) * q) + pos;
    const int bx = wg / gy, by = wg - bx * gy;
    const int bm = bx * 128, bn = by * 128;
    // gll staging map: wave w covers rows [w*32, w*32+32)
    const int srow = (w << 5) + (lane >> 2);
    const int k8 = (lane & 3) << 3;
    const int lb = w << 11;
    f32x4 acc[4][4] = {};

    // ASRC==0 A staging: thread covers row t>>1, k-quarter (t&1)*16
    const int arow = t >> 1, kq = (t & 1) << 4;
    int gmA = bm + arow; if (gmA >= M) gmA = M - 1;
    const float* aBase = (ASRC == 0) ? (Af + (size_t)gmA * ldAf) : nullptr;
    float aR[16];

    auto LOADA = [&](int k0) {
#pragma unroll
        for (int j = 0; j < 16; ++j) aR[j] = aBase[k0 + kq + j];
    };
    auto WRITEA = [&](int k0) {
        short8 hv0, lv0, hv1, lv1;
#pragma unroll
        for (int j = 0; j < 8; ++j) {
            float v = (k0 + kq + j < Ktrue) ? aR[j] : 0.f;
            u16 hh = f2bf(v);
            hv0[j] = (short)hh;
            lv0[j] = (short)f2bf(v - bf2f(hh));
        }
#pragma unroll
        for (int j = 0; j < 8; ++j) {
            float v = (k0 + kq + 8 + j < Ktrue) ? aR[8 + j] : 0.f;
            u16 hh = f2bf(v);
            hv1[j] = (short)hh;
            lv1[j] = (short)f2bf(v - bf2f(hh));
        }
        const int wa = arow * 32 + kq;
        *(short8*)&Ah[wa] = hv0;  *(short8*)&Ah[wa + 8] = hv1;
        *(short8*)&Al[wa] = lv0;  *(short8*)&Al[wa + 8] = lv1;
    };

    if (ASRC == 0) LOADA(0);
    for (int k0 = 0; k0 < K; k0 += 32) {
        gll16(Bhi + (size_t)(bn + srow) * ldB + k0 + k8, (u16*)((char*)Bh + lb));
        gll16(Bhi + (size_t)(bn + srow + 16) * ldB + k0 + k8, (u16*)((char*)Bh + lb + 1024));
        gll16(Blo + (size_t)(bn + srow) * ldB + k0 + k8, (u16*)((char*)Bl + lb));
        gll16(Blo + (size_t)(bn + srow + 16) * ldB + k0 + k8, (u16*)((char*)Bl + lb + 1024));
        if (ASRC == 0) {
            WRITEA(k0);
        } else {
            gll16(Ahi + (size_t)(bm + srow) * ldA + k0 + k8, (u16*)((char*)Ah + lb));
            gll16(Ahi + (size_t)(bm + srow + 16) * ldA + k0 + k8, (u16*)((char*)Ah + lb + 1024));
            gll16(Alo + (size_t)(bm + srow) * ldA + k0 + k8, (u16*)((char*)Al + lb));
            gll16(Alo + (size_t)(bm + srow + 16) * ldA + k0 + k8, (u16*)((char*)Al + lb + 1024));
        }
        __syncthreads();
        if (ASRC == 0 && k0 + 32 < K) LOADA(k0 + 32);  // issue early, hide under MFMA
        short8 fah[4], fal[4];
#pragma unroll
        for (int mi = 0; mi < 4; ++mi) {
            const int off = (wr * 64 + mi * 16 + r16) * 32 + kg * 8;
            fah[mi] = *(const short8*)&Ah[off];
            fal[mi] = *(const short8*)&Al[off];
        }
#pragma unroll
        for (int ni = 0; ni < 4; ++ni) {
            const int off = (wc * 64 + ni * 16 + r16) * 32 + kg * 8;
            const short8 fbh = *(const short8*)&Bh[off];
            const short8 fbl = *(const short8*)&Bl[off];
#pragma unroll
            for (int mi = 0; mi < 4; ++mi) {
                acc[mi][ni] = __builtin_amdgcn_mfma_f32_16x16x32_bf16(fah[mi], fbh, acc[mi][ni], 0, 0, 0);
                acc[mi][ni] = __builtin_amdgcn_mfma_f32_16x16x32_bf16(fal[mi], fbh, acc[mi][ni], 0, 0, 0);
                acc[mi][ni] = __builtin_amdgcn_mfma_f32_16x16x32_bf16(fah[mi], fbl, acc[mi][ni], 0, 0, 0);
            }
        }
        __syncthreads();
    }

    const float thr = (EPI == 2) ? *thrp : 0.f;
#pragma unroll
    for (int mi = 0; mi < 4; ++mi) {
#pragma unroll
        for (int i = 0; i < 4; ++i) {
            const int m = bm + wr * 64 + mi * 16 + kg * 4 + i;
            if (m >= M) continue;
            const float rs = (OUTM == 2) ? rowscale[m] : 1.f;
#pragma unroll
            for (int ni = 0; ni < 4; ++ni) {
                const int n = bn + wc * 64 + ni * 16 + r16;
                float z = acc[mi][ni][i];
                if (EPI >= 1) {
                    z += (n < Ntrue) ? bias[n] : 0.f;
                    z = (EPI == 1) ? fmaxf(z, 0.f) : fmaxf(z - thr, 0.f);
                }
                if (OUTM == 0) {
                    if (n < Ntrue) Cf[(size_t)m * ldC + n] = z;
                } else if (OUTM == 2) {
                    if (n < Ntrue) Cf[(size_t)m * ldC + n] = z * rs;
                } else {
                    if (n < ldC) {
                        if (n >= Ntrue) z = 0.f;
                        u16 h = f2bf(z);
                        size_t o = (size_t)m * ldC + n;
                        Chi[o] = h;
                        Clo[o] = f2bf(z - bf2f(h));
                    }
                }
            }
        }
    }
}

// ---------------- XCD-sliced GCN aggregation -------------------------------
// slice keyed to blockIdx%8 (round-robin XCD dispatch) -> each XCD's gathers
// stay within a 3.75MB table slice (L2-resident). Half-wave (32 lanes) per
// node-slice; rows prescaled by dinv[src]; out = elu(dinv[n]*sum + b).
// NS = slices (8 for F=256, 4 for F=128); WB=1 pair out, WB=0 f32 out.

template <int NS, int WB>
__global__ __launch_bounds__(256) void k_aggs(
    const float* __restrict__ hWs, const float* __restrict__ dinv,
    const unsigned* __restrict__ rowptr, const int* __restrict__ colsrc,
    const float* __restrict__ bias, float* __restrict__ outf,
    u16* __restrict__ oh, u16* __restrict__ ol, int N) {
    const int F = NS * 32;
    const int m = blockIdx.x & 7;
    const int g = blockIdx.x >> 3;
    const int slice = (NS == 8) ? m : (m & 3);
    const int nbase = (NS == 8) ? (g << 3) : ((g << 4) + ((m >> 2) << 3));
    const int wave = threadIdx.x >> 6;
    const int half = (threadIdx.x >> 5) & 1;
    const int ln = threadIdx.x & 31;
    const int n = nbase + (wave << 1) + half;
    if (n >= N) return;
    const int fb = (slice << 5) + ln;
    const float* __restrict__ hb = hWs + fb;
    float acc = hb[(size_t)n * F];              // self row (prescaled)
    unsigned idx = rowptr[n];
    const unsigned end = rowptr[n + 1];
    for (; idx + 4 <= end; idx += 4) {
        int s0 = colsrc[idx], s1 = colsrc[idx + 1];
        int s2 = colsrc[idx + 2], s3 = colsrc[idx + 3];
        float a0 = hb[(size_t)s0 * F], a1 = hb[(size_t)s1 * F];
        float a2 = hb[(size_t)s2 * F], a3 = hb[(size_t)s3 * F];
        acc += (a0 + a1) + (a2 + a3);
    }
    for (; idx < end; ++idx) acc += hb[(size_t)colsrc[idx] * F];
    float z = dinv[n] * acc + bias[fb];
    z = (z > 0.f) ? z : expm1f(z);
    const size_t o = (size_t)n * F + fb;
    if (WB) {
        u16 h = f2bf(z);
        oh[o] = h;
        ol[o] = f2bf(z - bf2f(h));
    } else {
        outf[o] = z;
    }
}

// ---------------- pair readout ----------------

__global__ __launch_bounds__(256) void k_pairs(
    const float* __restrict__ h, const int* __restrict__ i1, const int* __restrict__ i2,
    u16* __restrict__ xh, u16* __restrict__ xl, int B) {
    const int wave = threadIdx.x >> 6;
    const int lane = threadIdx.x & 63;
    const int p = blockIdx.x * 4 + wave;
    if (p >= B) return;
    const int a = i1[p], b = i2[p];
    float v0 = h[(size_t)a * 128 + lane];
    float v1 = h[(size_t)a * 128 + 64 + lane];
    float v2 = h[(size_t)b * 128 + lane];
    float v3 = h[(size_t)b * 128 + 64 + lane];
    float ss = v0 * v0 + v1 * v1 + v2 * v2 + v3 * v3;
#pragma unroll
    for (int o = 32; o > 0; o >>= 1) ss += __shfl_xor(ss, o, 64);
    float scale = 1.0f / fmaxf(sqrtf(ss), 1e-12f);
    size_t o = (size_t)p * 256;
    float vv[4] = {v0 * scale, v1 * scale, v2 * scale, v3 * scale};
#pragma unroll
    for (int j = 0; j < 4; ++j) {
        u16 hh = f2bf(vv[j]);
        xh[o + j * 64 + lane] = hh;
        xl[o + j * 64 + lane] = f2bf(vv[j] - bf2f(hh));
    }
}

__global__ __launch_bounds__(256) void k_out(
    const float* __restrict__ x, const float* __restrict__ W, const float* __restrict__ b,
    float* __restrict__ out, int B) {
    const int wave = threadIdx.x >> 6;
    const int lane = threadIdx.x & 63;
    const int p = blockIdx.x * 4 + wave;
    if (p >= B) return;
    float v = x[(size_t)p * 64 + lane];
    float s0 = v * W[lane * 2 + 0];
    float s1 = v * W[lane * 2 + 1];
#pragma unroll
    for (int o = 32; o > 0; o >>= 1) {
        s0 += __shfl_xor(s0, o, 64);
        s1 += __shfl_xor(s1, o, 64);
    }
    if (lane == 0) {
        out[p * 2 + 0] = s0 + b[0];
        out[p * 2 + 1] = s1 + b[1];
    }
}

// ---------------- launcher ----------------

extern "C" void kernel_launch(void* const* d_in, const int* in_sizes, int n_in,
                              void* d_out, int out_size, void* d_ws, size_t ws_size,
                              hipStream_t stream) {
    const float* cid = (const float*)d_in[0];
    const int* le   = (const int*)d_in[1];
    const int* i1   = (const int*)d_in[2];
    const int* i2   = (const int*)d_in[3];
    const float* thr = (const float*)d_in[4];
    const float* W2 = (const float*)d_in[5];  const float* b2 = (const float*)d_in[6];
    const float* W3 = (const float*)d_in[7];  const float* b3 = (const float*)d_in[8];
    const float* gW[5] = {(const float*)d_in[9],  (const float*)d_in[11], (const float*)d_in[13],
                          (const float*)d_in[15], (const float*)d_in[17]};
    const float* gB[5] = {(const float*)d_in[10], (const float*)d_in[12], (const float*)d_in[14],
                          (const float*)d_in[16], (const float*)d_in[18]};
    const float* fc1W = (const float*)d_in[19]; const float* fc1b = (const float*)d_in[20];
    const float* fc2W = (const float*)d_in[21]; const float* fc2b = (const float*)d_in[22];
    const float* fc3W = (const float*)d_in[23]; const float* fc3b = (const float*)d_in[24];
    const float* oW   = (const float*)d_in[25]; const float* ob   = (const float*)d_in[26];

    const int N = NNODES, E = NEDGES, B = NPAIRS;
    char* ws = (char*)d_ws;
    const bool big = ws_size >= 230000000ull;

    // graph scratch + weights (fixed region)
    unsigned* cnt    = (unsigned*)(ws + 0);
    unsigned* cursor = (unsigned*)(ws + 120064);
    unsigned* rowptr = (unsigned*)(ws + 240128);
    int*      colsrc = (int*)     (ws + 360192);
    unsigned* loc    = (unsigned*)(ws + 360192);            // scan temp (dead before fill)
    unsigned* part   = (unsigned*)(ws + 360192 + 122880);   // 118 partials
    float*    dinv   = (float*)   (ws + 2280192);
    u16* W2th = (u16*)(ws + 2400256);  u16* W2tl = (u16*)(ws + 4005888);
    u16* W3th = (u16*)(ws + 5611520);  u16* W3tl = (u16*)(ws + 6070272);
    u16* g1h  = (u16*)(ws + 6529024);  u16* g1l  = (u16*)(ws + 6660096);
    u16* g2h  = (u16*)(ws + 6791168);  u16* g2l  = (u16*)(ws + 6922240);
    u16* g3h  = (u16*)(ws + 7053312);  u16* g3l  = (u16*)(ws + 7184384);
    u16* g4h  = (u16*)(ws + 7315456);  u16* g4l  = (u16*)(ws + 7380992);
    u16* g5h  = (u16*)(ws + 7446528);  u16* g5l  = (u16*)(ws + 7479296);
    u16* f1h  = (u16*)(ws + 7512064);  u16* f1l  = (u16*)(ws + 8036352);
    u16* f2h  = (u16*)(ws + 8560640);  u16* f2l  = (u16*)(ws + 9084928);
    u16* f3h  = (u16*)(ws + 9609216);  u16* f3l  = (u16*)(ws + 9674752);

    u16 *cidh = nullptr, *cidl = nullptr;
    u16 *x1h, *x1l, *x2h, *x2l, *hAh, *hAl, *xch, *xcl, *t1h, *t1l, *t2h, *t2l;
    float *hWs, *hfin, *t3;
    if (big) {
        const size_t CB = 9740288;
        const size_t XB = CB + 2ull * 53903360;
        cidh = (u16*)(ws + CB);
        cidl = (u16*)(ws + CB + 53903360);
        x1h  = (u16*)(ws + XB);
        x1l  = (u16*)(ws + XB + 53903360);
        x2h  = (u16*)(ws + CB);
        x2l  = (u16*)(ws + CB + 15400960);
        hWs  = (float*)(ws + CB + 30801920);
        hfin = (float*)(ws + CB + 61603840);
        xch  = (u16*)(ws + CB + 76963840);
        xcl  = (u16*)(ws + CB + 79060992);
        t1h  = (u16*)(ws + CB + 81158144);
        t1l  = (u16*)(ws + CB + 89546752);
        t2h  = (u16*)(ws + CB + 97935360);
        t2l  = (u16*)(ws + CB + 100032512);
        t3   = (float*)(ws + CB + 102129664);
        hAh  = (u16*)(ws + XB);
        hAl  = (u16*)(ws + XB + 15400960);
    } else {
        const size_t X1 = 40542208;
        x2h = (u16*)(ws + 9740288);
        x2l = (u16*)(ws + 25141248);
        x1h = (u16*)(ws + X1);
        x1l = (u16*)(ws + X1 + 53903360);
        hWs  = (float*)(ws + X1);
        hAh  = (u16*)  (ws + X1 + 30801920);
        hAl  = (u16*)  (ws + X1 + 46202880);
        hfin = (float*)(ws + X1 + 61603840);
        xch  = (u16*)  (ws + X1 + 76963840);
        xcl  = (u16*)  (ws + X1 + 79060992);
        t1h  = (u16*)  (ws + X1 + 81158144);
        t1l  = (u16*)  (ws + X1 + 89546752);
        t2h  = (u16*)  (ws + X1 + 97935360);
        t2l  = (u16*)  (ws + X1 + 100032512);
        t3   = (float*)(ws + X1 + 102129664);
    }

    // --- graph prep ---
    hipMemsetAsync(cnt, 0, N * sizeof(unsigned), stream);
    hipMemsetAsync(cursor, 0, N * sizeof(unsigned), stream);
    k_count<<<(E + 255) / 256, 256, 0, stream>>>(le + E, cnt, E);
    k_dinv<<<(N + 255) / 256, 256, 0, stream>>>(cnt, dinv, N);
    const int NB = (N + 255) / 256;  // 118
    k_scan1<<<NB, 256, 0, stream>>>(cnt, loc, part, N);
    k_scan2<<<1, 64, 0, stream>>>(part, NB);
    k_scan3<<<NB, 256, 0, stream>>>(loc, part, rowptr, N);
    k_fill<<<(E + 255) / 256, 256, 0, stream>>>(le, le + E, rowptr, cursor, colsrc, E);

    // --- weight conversion (single launch) ---
    {
        WJobs js;
        int e = 0;
        auto set = [&](int i, const float* W, u16* Th, u16* Tl, int K, int Nn, int Kp, int Np) {
            e += (Np * Kp) / 256;
            js.j[i] = WJob{W, Th, Tl, K, Nn, Kp, Np, e};
        };
        set(0, W2, W2th, W2tl, 881, 881, 896, 896);
        set(1, W3, W3th, W3tl, 881, 256, 896, 256);
        set(2, gW[0], g1h, g1l, 256, 256, 256, 256);
        set(3, gW[1], g2h, g2l, 256, 256, 256, 256);
        set(4, gW[2], g3h, g3l, 256, 256, 256, 256);
        set(5, gW[3], g4h, g4l, 256, 128, 256, 128);
        set(6, gW[4], g5h, g5l, 128, 128, 128, 128);
        set(7, fc1W, f1h, f1l, 256, 1024, 256, 1024);
        set(8, fc2W, f2h, f2l, 1024, 256, 1024, 256);
        set(9, fc3W, f3h, f3l, 256, 64, 256, 128);
        k_wconv_all<<<e, 256, 0, stream>>>(js);
    }

    const int MB = (N + 127) / 128;  // 235

    // --- BasicBlock1 ---
    if (big) {
        k_aconv<<<(NNODES * 896 + 255) / 256, 256, 0, stream>>>(cid, cidh, cidl);
        k_mgemm<1, 2, 1><<<MB * 7, 256, 0, stream>>>(
            nullptr, 0, 0, cidh, cidl, 896, W2th, W2tl, 896, b2, thr, nullptr,
            nullptr, x1h, x1l, 896, N, 881, 896, 7);
    } else {
        k_mgemm<0, 2, 1><<<MB * 7, 256, 0, stream>>>(
            cid, 881, 881, nullptr, nullptr, 0, W2th, W2tl, 896, b2, thr, nullptr,
            nullptr, x1h, x1l, 896, N, 881, 896, 7);
    }
    k_mgemm<1, 1, 1><<<MB * 2, 256, 0, stream>>>(
        nullptr, 0, 0, x1h, x1l, 896, W3th, W3tl, 896, b3, nullptr, nullptr,
        nullptr, x2h, x2l, 256, N, 256, 896, 2);

    // --- 5 GCN layers ---
    const u16* wh[5] = {g1h, g2h, g3h, g4h, g5h};
    const u16* wl[5] = {g1l, g2l, g3l, g4l, g5l};
    const int fin[5]  = {256, 256, 256, 256, 128};
    const int fout[5] = {256, 256, 256, 128, 128};
    u16* curh = x2h;  u16* curl = x2l;
    for (int l = 0; l < 5; ++l) {
        const int gy = fout[l] / 128;
        k_mgemm<1, 0, 2><<<MB * gy, 256, 0, stream>>>(
            nullptr, 0, 0, curh, curl, fin[l], wh[l], wl[l], fin[l], nullptr, nullptr, dinv,
            hWs, nullptr, nullptr, fout[l], N, fout[l], fin[l], gy);
        if (l == 4) {
            k_aggs<4, 0><<<8 * ((N + 15) / 16), 256, 0, stream>>>(
                hWs, dinv, rowptr, colsrc, gB[l], hfin, nullptr, nullptr, N);
        } else if (fout[l] == 256) {
            u16* oh = (l & 1) ? x2h : hAh;
            u16* ol = (l & 1) ? x2l : hAl;
            k_aggs<8, 1><<<8 * ((N + 7) / 8), 256, 0, stream>>>(
                hWs, dinv, rowptr, colsrc, gB[l], nullptr, oh, ol, N);
            curh = oh; curl = ol;
        } else {  // l == 3, fout 128
            k_aggs<4, 1><<<8 * ((N + 15) / 16), 256, 0, stream>>>(
                hWs, dinv, rowptr, colsrc, gB[l], nullptr, x2h, x2l, N);
            curh = x2h; curl = x2l;
        }
    }

    // --- pair head ---
    k_pairs<<<(B + 3) / 4, 256, 0, stream>>>(hfin, i1, i2, xch, xcl, B);
    k_mgemm<1, 1, 1><<<32 * 8, 256, 0, stream>>>(
        nullptr, 0, 0, xch, xcl, 256, f1h, f1l, 256, fc1b, nullptr, nullptr,
        nullptr, t1h, t1l, 1024, B, 1024, 256, 8);
    k_mgemm<1, 1, 1><<<32 * 2, 256, 0, stream>>>(
        nullptr, 0, 0, t1h, t1l, 1024, f2h, f2l, 1024, fc2b, nullptr, nullptr,
        nullptr, t2h, t2l, 256, B, 256, 1024, 2);
    k_mgemm<1, 1, 0><<<32 * 1, 256, 0, stream>>>(
        nullptr, 0, 0, t2h, t2l, 256, f3h, f3l, 256, fc3b, nullptr, nullptr,
        t3, nullptr, nullptr, 64, B, 64, 256, 1);
    k_out<<<(B + 3) / 4, 256, 0, stream>>>(t3, oW, ob, (float*)d_out, B);
}